// Round 1
// baseline (417.975 us; speedup 1.0000x reference)
//
#include <hip/hip_runtime.h>
#include <math.h>

typedef _Float16 f16;
typedef _Float16 f16x8 __attribute__((ext_vector_type(8)));
typedef float f32x4 __attribute__((ext_vector_type(4)));

#define HEAD 128
#define EDIM 1536
#define NI   3200
#define HDIM 768
#define BATCH 4
#define SEQ  2048
#define MTOT (BATCH*SEQ)

// ---------------- prep kernels ----------------
__global__ __launch_bounds__(256) void cast_f32_f16_k(const float* __restrict__ in,
                                                      f16* __restrict__ out, int n4) {
  int i = blockIdx.x * 256 + threadIdx.x;
  if (i >= n4) return;
  float4 x = ((const float4*)in)[i];
  union { f16 h[4]; short4 s; } u;
  u.h[0] = (f16)x.x; u.h[1] = (f16)x.y; u.h[2] = (f16)x.z; u.h[3] = (f16)x.w;
  ((short4*)out)[i] = u.s;
}

// out[C][R] = in[R][C], f32 -> f16. grid = (C/32, R/32)
__global__ __launch_bounds__(256) void transpose_cast_k(const float* __restrict__ in, int ld_in,
                                                        f16* __restrict__ out, int ld_out) {
  __shared__ float tile[32][33];
  int c = threadIdx.x & 31, r0 = threadIdx.x >> 5;
  int ib = blockIdx.y * 32, jb = blockIdx.x * 32;
#pragma unroll
  for (int rr = 0; rr < 32; rr += 8)
    tile[r0 + rr][c] = in[(size_t)(ib + r0 + rr) * ld_in + jb + c];
  __syncthreads();
#pragma unroll
  for (int rr = 0; rr < 32; rr += 8)
    out[(size_t)(jb + r0 + rr) * ld_out + ib + c] = (f16)tile[c][r0 + rr];
}

// out[C][R] = in[R][C], f16 -> f16. grid = (C/32, R/32)
__global__ __launch_bounds__(256) void transpose_f16_k(const f16* __restrict__ in, int ld_in,
                                                       f16* __restrict__ out, int ld_out) {
  __shared__ f16 tile[32][33];
  int c = threadIdx.x & 31, r0 = threadIdx.x >> 5;
  int ib = blockIdx.y * 32, jb = blockIdx.x * 32;
#pragma unroll
  for (int rr = 0; rr < 32; rr += 8)
    tile[r0 + rr][c] = in[(size_t)(ib + r0 + rr) * ld_in + jb + c];
  __syncthreads();
#pragma unroll
  for (int rr = 0; rr < 32; rr += 8)
    out[(size_t)(jb + r0 + rr) * ld_out + ib + c] = tile[c][r0 + rr];
}

__global__ __launch_bounds__(256) void rope_tables_k(float* __restrict__ cosT,
                                                     float* __restrict__ sinT) {
  int id = blockIdx.x * 256 + threadIdx.x;   // < 2048*64
  int pos = id >> 6, i = id & 63;
  float ang = (float)pos / powf(10000.0f, (float)(2 * i) / 128.0f);
  float cv = cosf(ang), sv = sinf(ang);
  cosT[pos * HEAD + 2 * i]     = cv;
  cosT[pos * HEAD + 2 * i + 1] = cv;
  sinT[pos * HEAD + 2 * i]     = sv;
  sinT[pos * HEAD + 2 * i + 1] = sv;
}

__global__ __launch_bounds__(256) void addmask_k(const float* __restrict__ mask,
                                                 float* __restrict__ am) {
  int i = blockIdx.x * 256 + threadIdx.x;    // BATCH*SEQ
  am[i] = (1.0f - mask[i]) * -1e12f;
}

// ---------------- GEMM: C = A[M][K] * Bt[N][K]^T, f16 in, fp32 acc ----------------
// MODE 0: GEMM1  -> silu, split u/v to Xh; qk -> gamma/beta + RoPE -> Qh,Kh
// MODE 1: scores -> *1/sqrt(128) + addmask, f32 out
// MODE 2: attn@v -> * u elementwise, f16 out
// MODE 3: final  -> + bo, f32 out
template <int MODE>
__global__ __launch_bounds__(256, 2)
void gemm_bt(const f16* __restrict__ A, int lda,
             const f16* __restrict__ Bt, int ldb, int K,
             float* __restrict__ outF,
             f16* __restrict__ outH, f16* __restrict__ outH2, f16* __restrict__ outH3,
             const float* __restrict__ c0, const float* __restrict__ c1,
             const float* __restrict__ c2, const float* __restrict__ c3,
             const float* __restrict__ c4,
             const f16* __restrict__ hA) {
  __shared__ f16 As[128][40];   // 80B row pitch: 16B-aligned, spreads b128 reads over 8 slots
  __shared__ f16 Bs[128][40];
  const int m0 = blockIdx.y * 128, n0 = blockIdx.x * 128;
  const int t = threadIdx.x;
  const int lane = t & 63, w = t >> 6;
  const int wr = w >> 1, wc = w & 1;
  const int lr = lane & 15, kg = lane >> 4;

  f32x4 acc[4][4];
#pragma unroll
  for (int i = 0; i < 4; ++i)
#pragma unroll
    for (int j = 0; j < 4; ++j) acc[i][j] = f32x4{0.f, 0.f, 0.f, 0.f};

  for (int k0 = 0; k0 < K; k0 += 32) {
#pragma unroll
    for (int p = 0; p < 2; ++p) {
      int gid = t + p * 256;
      int row = gid >> 2, ch = gid & 3;
      *(float4*)&As[row][ch * 8] = *(const float4*)(A  + (size_t)(m0 + row) * lda + k0 + ch * 8);
      *(float4*)&Bs[row][ch * 8] = *(const float4*)(Bt + (size_t)(n0 + row) * ldb + k0 + ch * 8);
    }
    __syncthreads();
    f16x8 af[4], bf[4];
#pragma unroll
    for (int i = 0; i < 4; ++i) {
      af[i] = *(const f16x8*)&As[wr * 64 + i * 16 + lr][kg * 8];
      bf[i] = *(const f16x8*)&Bs[wc * 64 + i * 16 + lr][kg * 8];
    }
#pragma unroll
    for (int i = 0; i < 4; ++i)
#pragma unroll
      for (int j = 0; j < 4; ++j)
        acc[i][j] = __builtin_amdgcn_mfma_f32_16x16x32_f16(af[i], bf[j], acc[i][j], 0, 0, 0);
    __syncthreads();
  }

  // epilogue: C elem (row, col): col = lane&15, row = (lane>>4)*4 + r   [measured layout]
#pragma unroll
  for (int i = 0; i < 4; ++i) {
#pragma unroll
    for (int j = 0; j < 4; ++j) {
#pragma unroll
      for (int r = 0; r < 4; ++r) {
        int row = m0 + wr * 64 + i * 16 + kg * 4 + r;
        int col = n0 + wc * 64 + j * 16 + lr;
        float x = acc[i][j][r];
        if (MODE == 0) {
          float xb = x + c0[col];
          float s = xb / (1.0f + expf(-xb));       // silu
          if (blockIdx.x == 24) {                   // qk tile (cols 3072..3199), block-uniform
            int c = col - 3072;
            float pv = __shfl_xor(s, 1, 64);        // partner column c^1 lives in lane^1
            int pos = row & (SEQ - 1);
            float cv = c3[pos * HEAD + c], sv = c4[pos * HEAD + c];
            float q  = s  * c1[c]       + c2[c];
            float pq = pv * c1[c ^ 1]   + c2[c ^ 1];
            float x2q = (c & 1) ? pq : -pq;
            outH2[row * HEAD + c] = (f16)(q * cv + x2q * sv);
            float kk = s  * c1[128 + c]       + c2[128 + c];
            float pk = pv * c1[128 + (c ^ 1)] + c2[128 + (c ^ 1)];
            float x2k = (c & 1) ? pk : -pk;
            outH3[row * HEAD + c] = (f16)(kk * cv + x2k * sv);
          } else {
            outH[(size_t)row * 3072 + col] = (f16)s;   // u (col<1536) / v (col>=1536)
          }
        } else if (MODE == 1) {
          outF[(size_t)row * SEQ + col] = x * 0.08838834764831845f + c0[col];
        } else if (MODE == 2) {
          float uu = (float)hA[(size_t)row * 3072 + col];   // u
          outH[(size_t)row * EDIM + col] = (f16)(x * uu);
        } else {
          outF[(size_t)row * HDIM + col] = x + c0[col];
        }
      }
    }
  }
}

// ---------------- softmax_plus: one block per row, in-place f32 -> f16 ----------------
__global__ __launch_bounds__(256) void softmax_plus_k(float* __restrict__ S) {
  __shared__ float red[4];
  const int t = threadIdx.x;
  float* sr = S + (size_t)blockIdx.x * SEQ;
  float v[8];
  *(float4*)&v[0] = ((const float4*)sr)[t * 2];
  *(float4*)&v[4] = ((const float4*)sr)[t * 2 + 1];

  float cnt = 0.f;
#pragma unroll
  for (int i = 0; i < 8; ++i) cnt += (v[i] > -1e11f) ? 1.0f : 0.0f;
#pragma unroll
  for (int o = 32; o; o >>= 1) cnt += __shfl_xor(cnt, o, 64);
  if ((t & 63) == 0) red[t >> 6] = cnt;
  __syncthreads();
  cnt = red[0] + red[1] + red[2] + red[3];
  float scale = logf(fmaxf(cnt, 1.0f)) / logf(512.0f);

  float mx = -INFINITY;
#pragma unroll
  for (int i = 0; i < 8; ++i) { v[i] *= scale; mx = fmaxf(mx, v[i]); }
#pragma unroll
  for (int o = 32; o; o >>= 1) mx = fmaxf(mx, __shfl_xor(mx, o, 64));
  __syncthreads();
  if ((t & 63) == 0) red[t >> 6] = mx;
  __syncthreads();
  mx = fmaxf(fmaxf(red[0], red[1]), fmaxf(red[2], red[3]));

  float p[8], sum = 0.f;
#pragma unroll
  for (int i = 0; i < 8; ++i) { p[i] = expf(v[i] - mx); sum += p[i]; }
#pragma unroll
  for (int o = 32; o; o >>= 1) sum += __shfl_xor(sum, o, 64);
  __syncthreads();
  if ((t & 63) == 0) red[t >> 6] = sum;
  __syncthreads();
  sum = red[0] + red[1] + red[2] + red[3];
  float inv = 1.0f / sum;

  union { f16 h[8]; uint4 u4; } pk;
#pragma unroll
  for (int i = 0; i < 8; ++i) pk.h[i] = (f16)(p[i] * inv);
  ((uint4*)sr)[t] = pk.u4;   // all reads completed before last barrier
}

// ---------------- launch ----------------
extern "C" void kernel_launch(void* const* d_in, const int* in_sizes, int n_in,
                              void* d_out, int out_size, void* d_ws, size_t ws_size,
                              hipStream_t stream) {
  const float* hs    = (const float*)d_in[0];
  const float* mask  = (const float*)d_in[1];
  const float* Wi    = (const float*)d_in[2];
  const float* bi    = (const float*)d_in[3];
  const float* gamma = (const float*)d_in[4];
  const float* beta  = (const float*)d_in[5];
  const float* Wo    = (const float*)d_in[6];
  const float* bo    = (const float*)d_in[7];
  float* out = (float*)d_out;

  char* p = (char*)d_ws;
  auto alloc = [&](size_t b) { char* r = p; p += (b + 255) & ~(size_t)255; return r; };
  f16*   Xh   = (f16*)  alloc((size_t)MTOT * 3072 * 2);  // u|v
  f16*   Qh   = (f16*)  alloc((size_t)MTOT * HEAD * 2);
  f16*   Kh   = (f16*)  alloc((size_t)MTOT * HEAD * 2);
  f16*   Ah   = (f16*)  alloc((size_t)MTOT * HDIM * 2);
  f16*   WiT  = (f16*)  alloc((size_t)NI * HDIM * 2);
  f16*   WoT  = (f16*)  alloc((size_t)HDIM * EDIM * 2);
  float* cosT = (float*)alloc((size_t)SEQ * HEAD * 4);
  float* sinT = (float*)alloc((size_t)SEQ * HEAD * 4);
  float* am   = (float*)alloc((size_t)BATCH * SEQ * 4);
  float* Sws  = (float*)alloc((size_t)SEQ * SEQ * 4);   // per-batch reuse
  f16*   Vt   = (f16*)  alloc((size_t)EDIM * SEQ * 2);  // per-batch reuse
  f16*   G    = (f16*)  alloc((size_t)MTOT * EDIM * 2);

  cast_f32_f16_k<<<dim3(MTOT * HDIM / 4 / 256), 256, 0, stream>>>(hs, Ah, MTOT * HDIM / 4);
  transpose_cast_k<<<dim3(NI / 32, HDIM / 32), 256, 0, stream>>>(Wi, NI, WiT, HDIM);
  transpose_cast_k<<<dim3(HDIM / 32, EDIM / 32), 256, 0, stream>>>(Wo, HDIM, WoT, EDIM);
  rope_tables_k<<<dim3(SEQ * 64 / 256), 256, 0, stream>>>(cosT, sinT);
  addmask_k<<<dim3(BATCH * SEQ / 256), 256, 0, stream>>>(mask, am);

  gemm_bt<0><<<dim3(NI / 128, MTOT / 128), 256, 0, stream>>>(
      Ah, HDIM, WiT, HDIM, HDIM, nullptr, Xh, Qh, Kh,
      bi, gamma, beta, cosT, sinT, nullptr);

  for (int b = 0; b < BATCH; ++b) {
    transpose_f16_k<<<dim3(EDIM / 32, SEQ / 32), 256, 0, stream>>>(
        Xh + (size_t)b * SEQ * 3072 + 1536, 3072, Vt, SEQ);
    gemm_bt<1><<<dim3(SEQ / 128, SEQ / 128), 256, 0, stream>>>(
        Qh + (size_t)b * SEQ * HEAD, HEAD, Kh + (size_t)b * SEQ * HEAD, HEAD, HEAD,
        Sws, nullptr, nullptr, nullptr,
        am + b * SEQ, nullptr, nullptr, nullptr, nullptr, nullptr);
    softmax_plus_k<<<dim3(SEQ), 256, 0, stream>>>(Sws);
    gemm_bt<2><<<dim3(EDIM / 128, SEQ / 128), 256, 0, stream>>>(
        (const f16*)Sws, 4096, Vt, SEQ, SEQ,
        nullptr, G + (size_t)b * SEQ * EDIM, nullptr, nullptr,
        nullptr, nullptr, nullptr, nullptr, nullptr,
        Xh + (size_t)b * SEQ * 3072);
  }

  gemm_bt<3><<<dim3(HDIM / 128, MTOT / 128), 256, 0, stream>>>(
      G, EDIM, WoT, EDIM, EDIM, out, nullptr, nullptr, nullptr,
      bo, nullptr, nullptr, nullptr, nullptr, nullptr);
}

// Round 2
// 275.776 us; speedup vs baseline: 1.5156x; 1.5156x over previous
//
#include <hip/hip_runtime.h>
#include <math.h>

typedef _Float16 f16;
typedef _Float16 f16x8 __attribute__((ext_vector_type(8)));
typedef float f32x4 __attribute__((ext_vector_type(4)));

#define HEAD 128
#define EDIM 1536
#define NI   3200
#define HDIM 768
#define BATCH 4
#define SEQ  2048
#define MTOT (BATCH*SEQ)

__device__ __forceinline__ void gld_lds16(const void* g, void* l) {
  __builtin_amdgcn_global_load_lds(
      (const __attribute__((address_space(1))) void*)g,
      (__attribute__((address_space(3))) void*)l, 16, 0, 0);
}

// ---------------- prep kernels ----------------
__global__ __launch_bounds__(256) void cast_f32_f16_k(const float* __restrict__ in,
                                                      f16* __restrict__ out, int n4) {
  int i = blockIdx.x * 256 + threadIdx.x;
  if (i >= n4) return;
  float4 x = ((const float4*)in)[i];
  union { f16 h[4]; short4 s; } u;
  u.h[0] = (f16)x.x; u.h[1] = (f16)x.y; u.h[2] = (f16)x.z; u.h[3] = (f16)x.w;
  ((short4*)out)[i] = u.s;
}

// out[C][R] = in[R][C], f32 -> f16. grid = (C/32, R/32)
__global__ __launch_bounds__(256) void transpose_cast_k(const float* __restrict__ in, int ld_in,
                                                        f16* __restrict__ out, int ld_out) {
  __shared__ float tile[32][33];
  int c = threadIdx.x & 31, r0 = threadIdx.x >> 5;
  int ib = blockIdx.y * 32, jb = blockIdx.x * 32;
#pragma unroll
  for (int rr = 0; rr < 32; rr += 8)
    tile[r0 + rr][c] = in[(size_t)(ib + r0 + rr) * ld_in + jb + c];
  __syncthreads();
#pragma unroll
  for (int rr = 0; rr < 32; rr += 8)
    out[(size_t)(jb + r0 + rr) * ld_out + ib + c] = (f16)tile[c][r0 + rr];
}

// out[C][R] = in[R][C], f16 -> f16, batched over z. grid = (C/32, R/32, nb)
__global__ __launch_bounds__(256) void transpose_f16_k(const f16* __restrict__ in, int ld_in,
                                                       long long sIn,
                                                       f16* __restrict__ out, int ld_out,
                                                       long long sOut) {
  __shared__ f16 tile[32][33];
  in  += (size_t)blockIdx.z * sIn;
  out += (size_t)blockIdx.z * sOut;
  int c = threadIdx.x & 31, r0 = threadIdx.x >> 5;
  int ib = blockIdx.y * 32, jb = blockIdx.x * 32;
#pragma unroll
  for (int rr = 0; rr < 32; rr += 8)
    tile[r0 + rr][c] = in[(size_t)(ib + r0 + rr) * ld_in + jb + c];
  __syncthreads();
#pragma unroll
  for (int rr = 0; rr < 32; rr += 8)
    out[(size_t)(jb + r0 + rr) * ld_out + ib + c] = tile[c][r0 + rr];
}

__global__ __launch_bounds__(256) void rope_tables_k(float* __restrict__ cosT,
                                                     float* __restrict__ sinT) {
  int id = blockIdx.x * 256 + threadIdx.x;   // < 2048*64
  int pos = id >> 6, i = id & 63;
  float ang = (float)pos / powf(10000.0f, (float)(2 * i) / 128.0f);
  float cv = cosf(ang), sv = sinf(ang);
  cosT[pos * HEAD + 2 * i]     = cv;
  cosT[pos * HEAD + 2 * i + 1] = cv;
  sinT[pos * HEAD + 2 * i]     = sv;
  sinT[pos * HEAD + 2 * i + 1] = sv;
}

__global__ __launch_bounds__(256) void addmask_k(const float* __restrict__ mask,
                                                 float* __restrict__ am) {
  int i = blockIdx.x * 256 + threadIdx.x;    // BATCH*SEQ
  am[i] = (1.0f - mask[i]) * -1e12f;
}

// ---------------- GEMM: C = A[M][K] * Bt[N][K]^T, f16 in, fp32 acc ----------------
// m97 structure: 128x128 tile, BK=32, linear LDS, global_load_lds width=16.
// MODE 0: GEMM1  -> silu, split u/v to Xh; qk -> gamma/beta + RoPE -> Qh,Kh
// MODE 1: scores -> *1/sqrt(128) + addmask, f32 out   (batched via z)
// MODE 2: attn@v -> * u elementwise, f16 out          (batched via z)
// MODE 3: final  -> + bo, f32 out
template <int MODE>
__global__ __launch_bounds__(256, 4)
void gemm_bt(const f16* __restrict__ A, int lda, long long sA,
             const f16* __restrict__ Bt, int ldb, long long sB, int K,
             float* __restrict__ outF, long long sOutF,
             f16* __restrict__ outH, long long sOutH,
             f16* __restrict__ outH2, f16* __restrict__ outH3,
             const float* __restrict__ c0, long long sC0,
             const float* __restrict__ c1, const float* __restrict__ c2,
             const float* __restrict__ c3, const float* __restrict__ c4,
             const f16* __restrict__ hA, long long sHA) {
  __shared__ f16 As[128 * 32];   // linear: row pitch 64B (global_load_lds requires linear dest)
  __shared__ f16 Bs[128 * 32];
  const int z = blockIdx.z;
  const int m0 = blockIdx.y * 128, n0 = blockIdx.x * 128;
  const int t = threadIdx.x;
  const int lane = t & 63, w = t >> 6;
  const int wr = w >> 1, wc = w & 1;
  const int lr = lane & 15, kg = lane >> 4;

  const f16* Az = A  + (size_t)z * sA;
  const f16* Bz = Bt + (size_t)z * sB;

  // staging: thread t sources row (t>>2), 8-f16 chunk (t&3); LDS dest = wave base + lane*16
  const f16* ga = Az + (size_t)(m0 + (t >> 2)) * lda + (t & 3) * 8;
  const f16* gb = Bz + (size_t)(n0 + (t >> 2)) * ldb + (t & 3) * 8;
  char* lA = (char*)As + w * 1024;
  char* lB = (char*)Bs + w * 1024;

  f32x4 acc[4][4];
#pragma unroll
  for (int i = 0; i < 4; ++i)
#pragma unroll
    for (int j = 0; j < 4; ++j) acc[i][j] = f32x4{0.f, 0.f, 0.f, 0.f};

  for (int k0 = 0; k0 < K; k0 += 32) {
    gld_lds16(ga + k0,                       lA);
    gld_lds16(ga + (size_t)64 * lda + k0,    lA + 4096);
    gld_lds16(gb + k0,                       lB);
    gld_lds16(gb + (size_t)64 * ldb + k0,    lB + 4096);
    __syncthreads();                          // compiler drains vmcnt before barrier
    f16x8 af[4], bf[4];
#pragma unroll
    for (int i = 0; i < 4; ++i) {
      af[i] = *(const f16x8*)&As[(wr * 64 + i * 16 + lr) * 32 + kg * 8];
      bf[i] = *(const f16x8*)&Bs[(wc * 64 + i * 16 + lr) * 32 + kg * 8];
    }
#pragma unroll
    for (int i = 0; i < 4; ++i)
#pragma unroll
      for (int j = 0; j < 4; ++j)
        acc[i][j] = __builtin_amdgcn_mfma_f32_16x16x32_f16(af[i], bf[j], acc[i][j], 0, 0, 0);
    __syncthreads();
  }

  // epilogue: C elem (row, col): col = lane&15, row = (lane>>4)*4 + r   [measured layout]
#pragma unroll
  for (int i = 0; i < 4; ++i) {
#pragma unroll
    for (int j = 0; j < 4; ++j) {
#pragma unroll
      for (int r = 0; r < 4; ++r) {
        int row = m0 + wr * 64 + i * 16 + kg * 4 + r;
        int col = n0 + wc * 64 + j * 16 + lr;
        float x = acc[i][j][r];
        if (MODE == 0) {
          float xb = x + c0[col];
          float s = xb / (1.0f + expf(-xb));       // silu
          if (blockIdx.x == 24) {                   // qk tile (cols 3072..3199), block-uniform
            int c = col - 3072;
            float pv = __shfl_xor(s, 1, 64);        // partner column c^1 lives in lane^1
            int pos = row & (SEQ - 1);
            float cv = c3[pos * HEAD + c], sv = c4[pos * HEAD + c];
            float q  = s  * c1[c]       + c2[c];
            float pq = pv * c1[c ^ 1]   + c2[c ^ 1];
            float x2q = (c & 1) ? pq : -pq;
            outH2[row * HEAD + c] = (f16)(q * cv + x2q * sv);
            float kk = s  * c1[128 + c]       + c2[128 + c];
            float pk = pv * c1[128 + (c ^ 1)] + c2[128 + (c ^ 1)];
            float x2k = (c & 1) ? pk : -pk;
            outH3[row * HEAD + c] = (f16)(kk * cv + x2k * sv);
          } else {
            outH[(size_t)row * 3072 + col] = (f16)s;   // u (col<1536) / v (col>=1536)
          }
        } else if (MODE == 1) {
          (outF + (size_t)z * sOutF)[(size_t)row * SEQ + col] =
              x * 0.08838834764831845f + (c0 + (size_t)z * sC0)[col];
        } else if (MODE == 2) {
          float uu = (float)(hA + (size_t)z * sHA)[(size_t)row * 3072 + col];   // u
          (outH + (size_t)z * sOutH)[(size_t)row * EDIM + col] = (f16)(x * uu);
        } else {
          outF[(size_t)row * HDIM + col] = x + c0[col];
        }
      }
    }
  }
}

// ---------------- softmax_plus: one block per row, in-place f32 -> f16 ----------------
__global__ __launch_bounds__(256) void softmax_plus_k(float* __restrict__ S) {
  __shared__ float red[4];
  const int t = threadIdx.x;
  float* sr = S + (size_t)blockIdx.x * SEQ;
  float v[8];
  *(float4*)&v[0] = ((const float4*)sr)[t * 2];
  *(float4*)&v[4] = ((const float4*)sr)[t * 2 + 1];

  float cnt = 0.f;
#pragma unroll
  for (int i = 0; i < 8; ++i) cnt += (v[i] > -1e11f) ? 1.0f : 0.0f;
#pragma unroll
  for (int o = 32; o; o >>= 1) cnt += __shfl_xor(cnt, o, 64);
  if ((t & 63) == 0) red[t >> 6] = cnt;
  __syncthreads();
  cnt = red[0] + red[1] + red[2] + red[3];
  float scale = logf(fmaxf(cnt, 1.0f)) / logf(512.0f);

  float mx = -INFINITY;
#pragma unroll
  for (int i = 0; i < 8; ++i) { v[i] *= scale; mx = fmaxf(mx, v[i]); }
#pragma unroll
  for (int o = 32; o; o >>= 1) mx = fmaxf(mx, __shfl_xor(mx, o, 64));
  __syncthreads();
  if ((t & 63) == 0) red[t >> 6] = mx;
  __syncthreads();
  mx = fmaxf(fmaxf(red[0], red[1]), fmaxf(red[2], red[3]));

  float p[8], sum = 0.f;
#pragma unroll
  for (int i = 0; i < 8; ++i) { p[i] = expf(v[i] - mx); sum += p[i]; }
#pragma unroll
  for (int o = 32; o; o >>= 1) sum += __shfl_xor(sum, o, 64);
  __syncthreads();
  if ((t & 63) == 0) red[t >> 6] = sum;
  __syncthreads();
  sum = red[0] + red[1] + red[2] + red[3];
  float inv = 1.0f / sum;

  union { f16 h[8]; uint4 u4; } pk;
#pragma unroll
  for (int i = 0; i < 8; ++i) pk.h[i] = (f16)(p[i] * inv);
  ((uint4*)sr)[t] = pk.u4;   // all reads completed before last barrier
}

// ---------------- launch ----------------
extern "C" void kernel_launch(void* const* d_in, const int* in_sizes, int n_in,
                              void* d_out, int out_size, void* d_ws, size_t ws_size,
                              hipStream_t stream) {
  const float* hs    = (const float*)d_in[0];
  const float* mask  = (const float*)d_in[1];
  const float* Wi    = (const float*)d_in[2];
  const float* bi    = (const float*)d_in[3];
  const float* gamma = (const float*)d_in[4];
  const float* beta  = (const float*)d_in[5];
  const float* Wo    = (const float*)d_in[6];
  const float* bo    = (const float*)d_in[7];
  float* out = (float*)d_out;

  // batched path needs ~194 MB; fall back to per-batch serial if ws is smaller
  const int nb = (ws_size >= ((size_t)196 << 20)) ? BATCH : 1;

  char* p = (char*)d_ws;
  auto alloc = [&](size_t b) { char* r = p; p += (b + 255) & ~(size_t)255; return r; };
  f16*   Xh   = (f16*)  alloc((size_t)MTOT * 3072 * 2);  // u|v
  f16*   Qh   = (f16*)  alloc((size_t)MTOT * HEAD * 2);
  f16*   Kh   = (f16*)  alloc((size_t)MTOT * HEAD * 2);
  f16*   Ah   = (f16*)  alloc((size_t)MTOT * HDIM * 2);
  f16*   WiT  = (f16*)  alloc((size_t)NI * HDIM * 2);
  f16*   WoT  = (f16*)  alloc((size_t)HDIM * EDIM * 2);
  float* cosT = (float*)alloc((size_t)SEQ * HEAD * 4);
  float* sinT = (float*)alloc((size_t)SEQ * HEAD * 4);
  float* am   = (float*)alloc((size_t)BATCH * SEQ * 4);
  f16*   G    = (f16*)  alloc((size_t)MTOT * EDIM * 2);
  float* Sws  = (float*)alloc((size_t)nb * SEQ * SEQ * 4);
  f16*   Vt   = (f16*)  alloc((size_t)nb * EDIM * SEQ * 2);

  cast_f32_f16_k<<<dim3(MTOT * HDIM / 4 / 256), 256, 0, stream>>>(hs, Ah, MTOT * HDIM / 4);
  transpose_cast_k<<<dim3(NI / 32, HDIM / 32), 256, 0, stream>>>(Wi, NI, WiT, HDIM);
  transpose_cast_k<<<dim3(HDIM / 32, EDIM / 32), 256, 0, stream>>>(Wo, HDIM, WoT, EDIM);
  rope_tables_k<<<dim3(SEQ * 64 / 256), 256, 0, stream>>>(cosT, sinT);
  addmask_k<<<dim3(BATCH * SEQ / 256), 256, 0, stream>>>(mask, am);

  gemm_bt<0><<<dim3(NI / 128, MTOT / 128, 1), 256, 0, stream>>>(
      Ah, HDIM, 0, WiT, HDIM, 0, HDIM,
      nullptr, 0, Xh, 0, Qh, Kh,
      bi, 0, gamma, beta, cosT, sinT, nullptr, 0);

  for (int b0 = 0; b0 < BATCH; b0 += nb) {
    transpose_f16_k<<<dim3(EDIM / 32, SEQ / 32, nb), 256, 0, stream>>>(
        Xh + (size_t)b0 * SEQ * 3072 + 1536, 3072, (long long)SEQ * 3072,
        Vt, SEQ, (long long)EDIM * SEQ);
    gemm_bt<1><<<dim3(SEQ / 128, SEQ / 128, nb), 256, 0, stream>>>(
        Qh + (size_t)b0 * SEQ * HEAD, HEAD, (long long)SEQ * HEAD,
        Kh + (size_t)b0 * SEQ * HEAD, HEAD, (long long)SEQ * HEAD, HEAD,
        Sws, (long long)SEQ * SEQ, nullptr, 0, nullptr, nullptr,
        am + b0 * SEQ, SEQ, nullptr, nullptr, nullptr, nullptr, nullptr, 0);
    softmax_plus_k<<<dim3(nb * SEQ), 256, 0, stream>>>(Sws);
    gemm_bt<2><<<dim3(EDIM / 128, SEQ / 128, nb), 256, 0, stream>>>(
        (const f16*)Sws, 4096, (long long)SEQ * SEQ * 2,
        Vt, SEQ, (long long)EDIM * SEQ, SEQ,
        nullptr, 0, G + (size_t)b0 * SEQ * EDIM, (long long)SEQ * EDIM, nullptr, nullptr,
        nullptr, 0, nullptr, nullptr, nullptr, nullptr,
        Xh + (size_t)b0 * SEQ * 3072, (long long)SEQ * 3072);
  }

  gemm_bt<3><<<dim3(HDIM / 128, MTOT / 128, 1), 256, 0, stream>>>(
      G, EDIM, 0, WoT, EDIM, 0, EDIM,
      out, 0, nullptr, 0, nullptr, nullptr,
      bo, 0, nullptr, nullptr, nullptr, nullptr, nullptr, 0);
}

// Round 3
// 260.038 us; speedup vs baseline: 1.6074x; 1.0605x over previous
//
#include <hip/hip_runtime.h>
#include <math.h>

typedef _Float16 f16;
typedef _Float16 f16x8 __attribute__((ext_vector_type(8)));
typedef float f32x4 __attribute__((ext_vector_type(4)));

#define HEAD 128
#define EDIM 1536
#define NI   3200
#define HDIM 768
#define BATCH 4
#define SEQ  2048
#define MTOT (BATCH*SEQ)

__device__ __forceinline__ void gld_lds16(const void* g, void* l) {
  __builtin_amdgcn_global_load_lds(
      (const __attribute__((address_space(1))) void*)g,
      (__attribute__((address_space(3))) void*)l, 16, 0, 0);
}

// ---------------- prep kernels ----------------
__global__ __launch_bounds__(256) void cast_f32_f16_k(const float* __restrict__ in,
                                                      f16* __restrict__ out, int n4) {
  int i = blockIdx.x * 256 + threadIdx.x;
  if (i >= n4) return;
  float4 x = ((const float4*)in)[i];
  union { f16 h[4]; short4 s; } u;
  u.h[0] = (f16)x.x; u.h[1] = (f16)x.y; u.h[2] = (f16)x.z; u.h[3] = (f16)x.w;
  ((short4*)out)[i] = u.s;
}

// out[C][R] = in[R][C], f32 -> f16. grid = (C/32, R/32)
__global__ __launch_bounds__(256) void transpose_cast_k(const float* __restrict__ in, int ld_in,
                                                        f16* __restrict__ out, int ld_out) {
  __shared__ float tile[32][33];
  int c = threadIdx.x & 31, r0 = threadIdx.x >> 5;
  int ib = blockIdx.y * 32, jb = blockIdx.x * 32;
#pragma unroll
  for (int rr = 0; rr < 32; rr += 8)
    tile[r0 + rr][c] = in[(size_t)(ib + r0 + rr) * ld_in + jb + c];
  __syncthreads();
#pragma unroll
  for (int rr = 0; rr < 32; rr += 8)
    out[(size_t)(jb + r0 + rr) * ld_out + ib + c] = (f16)tile[c][r0 + rr];
}

// out[C][R] = in[R][C], f16 -> f16, batched over z. grid = (C/32, R/32, nb)
__global__ __launch_bounds__(256) void transpose_f16_k(const f16* __restrict__ in, int ld_in,
                                                       long long sIn,
                                                       f16* __restrict__ out, int ld_out,
                                                       long long sOut) {
  __shared__ f16 tile[32][33];
  in  += (size_t)blockIdx.z * sIn;
  out += (size_t)blockIdx.z * sOut;
  int c = threadIdx.x & 31, r0 = threadIdx.x >> 5;
  int ib = blockIdx.y * 32, jb = blockIdx.x * 32;
#pragma unroll
  for (int rr = 0; rr < 32; rr += 8)
    tile[r0 + rr][c] = in[(size_t)(ib + r0 + rr) * ld_in + jb + c];
  __syncthreads();
#pragma unroll
  for (int rr = 0; rr < 32; rr += 8)
    out[(size_t)(jb + r0 + rr) * ld_out + ib + c] = tile[c][r0 + rr];
}

__global__ __launch_bounds__(256) void rope_tables_k(float* __restrict__ cosT,
                                                     float* __restrict__ sinT) {
  int id = blockIdx.x * 256 + threadIdx.x;   // < 2048*64
  int pos = id >> 6, i = id & 63;
  float ang = (float)pos / powf(10000.0f, (float)(2 * i) / 128.0f);
  float cv = cosf(ang), sv = sinf(ang);
  cosT[pos * HEAD + 2 * i]     = cv;
  cosT[pos * HEAD + 2 * i + 1] = cv;
  sinT[pos * HEAD + 2 * i]     = sv;
  sinT[pos * HEAD + 2 * i + 1] = sv;
}

__global__ __launch_bounds__(256) void addmask_k(const float* __restrict__ mask,
                                                 float* __restrict__ am) {
  int i = blockIdx.x * 256 + threadIdx.x;    // BATCH*SEQ
  am[i] = (1.0f - mask[i]) * -1e12f;
}

// ---------------- GEMM: C = A[M][K] * Bt[N][K]^T, f16 in, fp32 acc ----------------
// 128x128 tile, BK=32, linear LDS, global_load_lds width=16,
// 2-phase double-buffer (T3 minimum recipe): stage(next) issued BEFORE compute(cur),
// one barrier per phase -> load latency hides under MFMA+ds_read.
// MODE 0: GEMM1  -> silu, split u/v to Xh; qk -> gamma/beta + RoPE -> Qh,Kh
// MODE 1: scores -> *1/sqrt(128) + addmask, f32 out   (batched via z)
// MODE 2: attn@v -> * u elementwise, f16 out          (batched via z)
// MODE 3: final  -> + bo, f32 out
template <int MODE>
__global__ __launch_bounds__(256, 4)
void gemm_bt(const f16* __restrict__ A, int lda, long long sA,
             const f16* __restrict__ Bt, int ldb, long long sB, int K,
             float* __restrict__ outF, long long sOutF,
             f16* __restrict__ outH, long long sOutH,
             f16* __restrict__ outH2, f16* __restrict__ outH3,
             const float* __restrict__ c0, long long sC0,
             const float* __restrict__ c1, const float* __restrict__ c2,
             const float* __restrict__ c3, const float* __restrict__ c4,
             const f16* __restrict__ hA, long long sHA) {
  __shared__ f16 As0[128 * 32];   // linear (global_load_lds requires linear dest)
  __shared__ f16 As1[128 * 32];
  __shared__ f16 Bs0[128 * 32];
  __shared__ f16 Bs1[128 * 32];
  const int z = blockIdx.z;
  const int m0 = blockIdx.y * 128, n0 = blockIdx.x * 128;
  const int t = threadIdx.x;
  const int lane = t & 63, w = t >> 6;
  const int wr = w >> 1, wc = w & 1;
  const int lr = lane & 15, kg = lane >> 4;

  const f16* Az = A  + (size_t)z * sA;
  const f16* Bz = Bt + (size_t)z * sB;

  // staging: thread t sources row (t>>2), 8-f16 chunk (t&3); LDS dest = wave base + lane*16
  const f16* ga = Az + (size_t)(m0 + (t >> 2)) * lda + (t & 3) * 8;
  const f16* gb = Bz + (size_t)(n0 + (t >> 2)) * ldb + (t & 3) * 8;

  f32x4 acc[4][4];
#pragma unroll
  for (int i = 0; i < 4; ++i)
#pragma unroll
    for (int j = 0; j < 4; ++j) acc[i][j] = f32x4{0.f, 0.f, 0.f, 0.f};

  auto stage = [&](f16* AS, f16* BS, int kk) {
    gld_lds16(ga + kk,                    (char*)AS + w * 1024);
    gld_lds16(ga + (size_t)64 * lda + kk, (char*)AS + w * 1024 + 4096);
    gld_lds16(gb + kk,                    (char*)BS + w * 1024);
    gld_lds16(gb + (size_t)64 * ldb + kk, (char*)BS + w * 1024 + 4096);
  };
  auto compute = [&](const f16* AS, const f16* BS) {
    f16x8 af[4], bf[4];
#pragma unroll
    for (int i = 0; i < 4; ++i) {
      af[i] = *(const f16x8*)&AS[(wr * 64 + i * 16 + lr) * 32 + kg * 8];
      bf[i] = *(const f16x8*)&BS[(wc * 64 + i * 16 + lr) * 32 + kg * 8];
    }
#pragma unroll
    for (int i = 0; i < 4; ++i)
#pragma unroll
      for (int j = 0; j < 4; ++j)
        acc[i][j] = __builtin_amdgcn_mfma_f32_16x16x32_f16(af[i], bf[j], acc[i][j], 0, 0, 0);
  };

  stage(As0, Bs0, 0);
  __syncthreads();                       // drains vmcnt(0): buf0 ready
  for (int k0 = 0; k0 < K; k0 += 64) {   // K % 64 == 0 for all modes
    if (k0 + 32 < K) stage(As1, Bs1, k0 + 32);  // in flight during compute(buf0)
    compute(As0, Bs0);
    __syncthreads();                     // all reads of buf0 done; buf1 writes drained
    if (k0 + 64 < K) stage(As0, Bs0, k0 + 64);  // in flight during compute(buf1)
    compute(As1, Bs1);
    __syncthreads();
  }

  // epilogue: C elem (row, col): col = lane&15, row = (lane>>4)*4 + r   [measured layout]
#pragma unroll
  for (int i = 0; i < 4; ++i) {
#pragma unroll
    for (int j = 0; j < 4; ++j) {
#pragma unroll
      for (int r = 0; r < 4; ++r) {
        int row = m0 + wr * 64 + i * 16 + kg * 4 + r;
        int col = n0 + wc * 64 + j * 16 + lr;
        float x = acc[i][j][r];
        if (MODE == 0) {
          float xb = x + c0[col];
          float s = xb * __builtin_amdgcn_rcpf(1.0f + __expf(-xb));   // silu, fast-math
          if (blockIdx.x == 24) {                   // qk tile (cols 3072..3199), block-uniform
            int c = col - 3072;
            float pv = __shfl_xor(s, 1, 64);        // partner column c^1 lives in lane^1
            int pos = row & (SEQ - 1);
            float cv = c3[pos * HEAD + c], sv = c4[pos * HEAD + c];
            float q  = s  * c1[c]       + c2[c];
            float pq = pv * c1[c ^ 1]   + c2[c ^ 1];
            float x2q = (c & 1) ? pq : -pq;
            outH2[row * HEAD + c] = (f16)(q * cv + x2q * sv);
            float kk = s  * c1[128 + c]       + c2[128 + c];
            float pk = pv * c1[128 + (c ^ 1)] + c2[128 + (c ^ 1)];
            float x2k = (c & 1) ? pk : -pk;
            outH3[row * HEAD + c] = (f16)(kk * cv + x2k * sv);
          } else {
            outH[(size_t)row * 3072 + col] = (f16)s;   // u (col<1536) / v (col>=1536)
          }
        } else if (MODE == 1) {
          (outF + (size_t)z * sOutF)[(size_t)row * SEQ + col] =
              x * 0.08838834764831845f + (c0 + (size_t)z * sC0)[col];
        } else if (MODE == 2) {
          float uu = (float)(hA + (size_t)z * sHA)[(size_t)row * 3072 + col];   // u
          (outH + (size_t)z * sOutH)[(size_t)row * EDIM + col] = (f16)(x * uu);
        } else {
          outF[(size_t)row * HDIM + col] = x + c0[col];
        }
      }
    }
  }
}

// ---------------- softmax_plus: one block per row, in-place f32 -> f16 ----------------
__global__ __launch_bounds__(256) void softmax_plus_k(float* __restrict__ S) {
  __shared__ float red[4];
  const int t = threadIdx.x;
  float* sr = S + (size_t)blockIdx.x * SEQ;
  float v[8];
  *(float4*)&v[0] = ((const float4*)sr)[t * 2];
  *(float4*)&v[4] = ((const float4*)sr)[t * 2 + 1];

  float cnt = 0.f;
#pragma unroll
  for (int i = 0; i < 8; ++i) cnt += (v[i] > -1e11f) ? 1.0f : 0.0f;
#pragma unroll
  for (int o = 32; o; o >>= 1) cnt += __shfl_xor(cnt, o, 64);
  if ((t & 63) == 0) red[t >> 6] = cnt;
  __syncthreads();
  cnt = red[0] + red[1] + red[2] + red[3];
  float scale = __logf(fmaxf(cnt, 1.0f)) * 0.16025848f;   // 1/ln(512)

  float mx = -INFINITY;
#pragma unroll
  for (int i = 0; i < 8; ++i) { v[i] *= scale; mx = fmaxf(mx, v[i]); }
#pragma unroll
  for (int o = 32; o; o >>= 1) mx = fmaxf(mx, __shfl_xor(mx, o, 64));
  __syncthreads();
  if ((t & 63) == 0) red[t >> 6] = mx;
  __syncthreads();
  mx = fmaxf(fmaxf(red[0], red[1]), fmaxf(red[2], red[3]));

  float p[8], sum = 0.f;
#pragma unroll
  for (int i = 0; i < 8; ++i) { p[i] = __expf(v[i] - mx); sum += p[i]; }
#pragma unroll
  for (int o = 32; o; o >>= 1) sum += __shfl_xor(sum, o, 64);
  __syncthreads();
  if ((t & 63) == 0) red[t >> 6] = sum;
  __syncthreads();
  sum = red[0] + red[1] + red[2] + red[3];
  float inv = __builtin_amdgcn_rcpf(sum);

  union { f16 h[8]; uint4 u4; } pk;
#pragma unroll
  for (int i = 0; i < 8; ++i) pk.h[i] = (f16)(p[i] * inv);
  ((uint4*)sr)[t] = pk.u4;   // all reads completed before last barrier
}

// ---------------- launch ----------------
extern "C" void kernel_launch(void* const* d_in, const int* in_sizes, int n_in,
                              void* d_out, int out_size, void* d_ws, size_t ws_size,
                              hipStream_t stream) {
  const float* hs    = (const float*)d_in[0];
  const float* mask  = (const float*)d_in[1];
  const float* Wi    = (const float*)d_in[2];
  const float* bi    = (const float*)d_in[3];
  const float* gamma = (const float*)d_in[4];
  const float* beta  = (const float*)d_in[5];
  const float* Wo    = (const float*)d_in[6];
  const float* bo    = (const float*)d_in[7];
  float* out = (float*)d_out;

  // batched path needs ~194 MB; fall back to per-batch serial if ws is smaller
  const int nb = (ws_size >= ((size_t)196 << 20)) ? BATCH : 1;

  char* p = (char*)d_ws;
  auto alloc = [&](size_t b) { char* r = p; p += (b + 255) & ~(size_t)255; return r; };
  f16*   Xh   = (f16*)  alloc((size_t)MTOT * 3072 * 2);  // u|v
  f16*   Qh   = (f16*)  alloc((size_t)MTOT * HEAD * 2);
  f16*   Kh   = (f16*)  alloc((size_t)MTOT * HEAD * 2);
  f16*   Ah   = (f16*)  alloc((size_t)MTOT * HDIM * 2);
  f16*   WiT  = (f16*)  alloc((size_t)NI * HDIM * 2);
  f16*   WoT  = (f16*)  alloc((size_t)HDIM * EDIM * 2);
  float* cosT = (float*)alloc((size_t)SEQ * HEAD * 4);
  float* sinT = (float*)alloc((size_t)SEQ * HEAD * 4);
  float* am   = (float*)alloc((size_t)BATCH * SEQ * 4);
  f16*   G    = (f16*)  alloc((size_t)MTOT * EDIM * 2);
  float* Sws  = (float*)alloc((size_t)nb * SEQ * SEQ * 4);
  f16*   Vt   = (f16*)  alloc((size_t)nb * EDIM * SEQ * 2);

  cast_f32_f16_k<<<dim3(MTOT * HDIM / 4 / 256), 256, 0, stream>>>(hs, Ah, MTOT * HDIM / 4);
  transpose_cast_k<<<dim3(NI / 32, HDIM / 32), 256, 0, stream>>>(Wi, NI, WiT, HDIM);
  transpose_cast_k<<<dim3(HDIM / 32, EDIM / 32), 256, 0, stream>>>(Wo, HDIM, WoT, EDIM);
  rope_tables_k<<<dim3(SEQ * 64 / 256), 256, 0, stream>>>(cosT, sinT);
  addmask_k<<<dim3(BATCH * SEQ / 256), 256, 0, stream>>>(mask, am);

  gemm_bt<0><<<dim3(NI / 128, MTOT / 128, 1), 256, 0, stream>>>(
      Ah, HDIM, 0, WiT, HDIM, 0, HDIM,
      nullptr, 0, Xh, 0, Qh, Kh,
      bi, 0, gamma, beta, cosT, sinT, nullptr, 0);

  for (int b0 = 0; b0 < BATCH; b0 += nb) {
    transpose_f16_k<<<dim3(EDIM / 32, SEQ / 32, nb), 256, 0, stream>>>(
        Xh + (size_t)b0 * SEQ * 3072 + 1536, 3072, (long long)SEQ * 3072,
        Vt, SEQ, (long long)EDIM * SEQ);
    gemm_bt<1><<<dim3(SEQ / 128, SEQ / 128, nb), 256, 0, stream>>>(
        Qh + (size_t)b0 * SEQ * HEAD, HEAD, (long long)SEQ * HEAD,
        Kh + (size_t)b0 * SEQ * HEAD, HEAD, (long long)SEQ * HEAD, HEAD,
        Sws, (long long)SEQ * SEQ, nullptr, 0, nullptr, nullptr,
        am + b0 * SEQ, SEQ, nullptr, nullptr, nullptr, nullptr, nullptr, 0);
    softmax_plus_k<<<dim3(nb * SEQ), 256, 0, stream>>>(Sws);
    gemm_bt<2><<<dim3(EDIM / 128, SEQ / 128, nb), 256, 0, stream>>>(
        (const f16*)Sws, 4096, (long long)SEQ * SEQ * 2,
        Vt, SEQ, (long long)EDIM * SEQ, SEQ,
        nullptr, 0, G + (size_t)b0 * SEQ * EDIM, (long long)SEQ * EDIM, nullptr, nullptr,
        nullptr, 0, nullptr, nullptr, nullptr, nullptr,
        Xh + (size_t)b0 * SEQ * 3072, (long long)SEQ * 3072);
  }

  gemm_bt<3><<<dim3(HDIM / 128, MTOT / 128, 1), 256, 0, stream>>>(
      G, EDIM, 0, WoT, EDIM, 0, EDIM,
      out, 0, nullptr, 0, nullptr, nullptr,
      bo, 0, nullptr, nullptr, nullptr, nullptr, nullptr, 0);
}